// Round 11
// baseline (45.623 us; speedup 1.0000x reference)
//
#include <hip/hip_runtime.h>

#define NG 48
#define NT 6                   // 4 A tiles per axis (8 cells)
#define NTILES (NT * NT * NT)  // 216
#define CAP 1536               // max atoms per (type,tile); expected max ~1010
#define MAXSEG 8
// ws layout:
//   [0,     2592)   int cnt[3*216]
//   [8192, ~2.0M)   u16 lists[3*216][CAP]
//   [2MiB, +10.6M)  float copies[3*216][MAXSEG][512]   (compact per-tile)
#define LISTS_OFF  8192
#define COPIES_OFF (2u << 20)

__device__ __forceinline__ float type_r(int type) {
    return (type == 0) ? 1.7f : ((type == 1) ? 1.55f : 1.52f);
}

// Phase 1 (two-level histogram): 512-atom blocks. Per-block LDS counts, ONE
// global atomicAdd per (block, active tile) to reserve a range, plain stores
// of atom indices into the reserved slots.
__global__ __launch_bounds__(512) void bin_kernel(
    const float* __restrict__ vC, const float* __restrict__ vN,
    const float* __restrict__ vO, int* __restrict__ cnt,
    unsigned short* __restrict__ lists, int natoms)
{
    const int type = blockIdx.y;
    const float r = type_r(type);
    const float b = 1.5f * r + 1e-3f;
    const float* __restrict__ vecs = (type == 0) ? vC : ((type == 1) ? vN : vO);
    const int tid  = threadIdx.x;
    const int atom = blockIdx.x * 512 + tid;

    __shared__ int lcnt[NTILES];
    __shared__ int lbase[NTILES];
    __shared__ int lfill[NTILES];
    if (tid < NTILES) { lcnt[tid] = 0; lfill[tid] = 0; }
    __syncthreads();

    int x0 = 1, x1 = 0, y0 = 1, y1 = 0, z0 = 1, z1 = 0;
    if (atom < natoms) {
        const float vx = vecs[3 * atom + 0] + 23.5f;  // vec = raw + 24 - 0.5
        const float vy = vecs[3 * atom + 1] + 23.5f;
        const float vz = vecs[3 * atom + 2] + 23.5f;
        // tile t intersects the 1.5r halo iff 4t > v - b - 3.5 and 4t < v + b
        x0 = max(0,      (int)floorf((vx - 3.5f - b) * 0.25f) + 1);
        x1 = min(NT - 1, (int)ceilf ((vx + b)        * 0.25f) - 1);
        y0 = max(0,      (int)floorf((vy - 3.5f - b) * 0.25f) + 1);
        y1 = min(NT - 1, (int)ceilf ((vy + b)        * 0.25f) - 1);
        z0 = max(0,      (int)floorf((vz - 3.5f - b) * 0.25f) + 1);
        z1 = min(NT - 1, (int)ceilf ((vz + b)        * 0.25f) - 1);
    }
    const bool has = (x0 <= x1) & (y0 <= y1) & (z0 <= z1);

    if (has)
        for (int tx = x0; tx <= x1; ++tx)
            for (int ty = y0; ty <= y1; ++ty)
                for (int tz = z0; tz <= z1; ++tz)
                    atomicAdd(&lcnt[(tx * NT + ty) * NT + tz], 1);   // LDS
    __syncthreads();

    if (tid < NTILES && lcnt[tid] > 0)
        lbase[tid] = atomicAdd(&cnt[type * NTILES + tid], lcnt[tid]);
    __syncthreads();

    if (has)
        for (int tx = x0; tx <= x1; ++tx)
            for (int ty = y0; ty <= y1; ++ty)
                for (int tz = z0; tz <= z1; ++tz) {
                    const int tl = (tx * NT + ty) * NT + tz;
                    const int p  = lbase[tl] + atomicAdd(&lfill[tl], 1);  // LDS
                    if (p < CAP)
                        lists[(size_t)(type * NTILES + tl) * CAP + p] =
                            (unsigned short)atom;
                }
}

// One atom evaluation against this thread's 4 cells (x,x+4)x(z,z+4).
#define EVAL_ATOM(a)                                                         \
    {                                                                        \
        const float dy   = (a).y - py;                                       \
        const float sy   = dy * dy;                                          \
        const float dz0  = (a).z - pz0;                                      \
        const float dz1  = (a).z - pz1;                                      \
        const float syz0 = fmaf(dz0, dz0, sy);                               \
        const float syz1 = fmaf(dz1, dz1, sy);                               \
        const float dx0  = (a).x - px0;                                      \
        const float dx1  = (a).x - px1;                                      \
        const float xx0  = dx0 * dx0;                                        \
        const float xx1  = dx1 * dx1;                                        \
        const float d200 = syz0 + xx0;                                       \
        const float d201 = syz1 + xx0;                                       \
        const float d210 = syz0 + xx1;                                       \
        const float d211 = syz1 + xx1;                                       \
        const bool h00 = d200 < r15sq, h01 = d201 < r15sq;                   \
        const bool h10 = d210 < r15sq, h11 = d211 < r15sq;                   \
        if (__ballot(h00 | h01 | h10 | h11) != 0ull) {                       \
            if (h00) { const float d = sqrtf(d200);                          \
                acc00 += (d < r) ? __expf(n2orr * d200)                      \
                                 : fmaf(c2a, d200, fmaf(-c2b, d, c2c)); }    \
            if (h01) { const float d = sqrtf(d201);                          \
                acc01 += (d < r) ? __expf(n2orr * d201)                      \
                                 : fmaf(c2a, d201, fmaf(-c2b, d, c2c)); }    \
            if (h10) { const float d = sqrtf(d210);                          \
                acc10 += (d < r) ? __expf(n2orr * d210)                      \
                                 : fmaf(c2a, d210, fmaf(-c2b, d, c2c)); }    \
            if (h11) { const float d = sqrtf(d211);                          \
                acc11 += (d < r) ? __expf(n2orr * d211)                      \
                                 : fmaf(c2a, d211, fmaf(-c2b, d, c2c)); }    \
        }                                                                    \
    }

// Phase 2: one 128-thread block per (segment, tile, type), segment-major.
// Thread owns 4 cells: (x, x+4) x (z, z+4) at one y — one LDS broadcast and
// one dy^2 amortized over 4 cells. j-loop hand-unrolled x2 for ILP.
__global__ __launch_bounds__(128) void gather_seg(
    const float* __restrict__ vC, const float* __restrict__ vN,
    const float* __restrict__ vO, const int* __restrict__ cnt,
    const unsigned short* __restrict__ lists, float* __restrict__ copies,
    int nseg)
{
    const int type = blockIdx.y;
    const float r = type_r(type);
    const float* __restrict__ vecs = (type == 0) ? vC : ((type == 1) ? vN : vO);

    const int s = blockIdx.x / NTILES;        // segment-major
    const int t = blockIdx.x - s * NTILES;

    const int lt  = type * NTILES + t;
    const int n   = min(cnt[lt], CAP);
    const int len = (n + nseg - 1) / nseg;    // 0 when n==0
    const int start = s * len;
    const int end   = min(n, start + len);
    if (start >= end) return;                 // empty segment: no work, no store

    const int tx = t / (NT * NT);
    const int ty = (t / NT) % NT;
    const int tz = t % NT;

    const int tid = threadIdx.x;              // 0..127
    const int lx  = tid >> 5;                 // 0..3 -> x and x+4
    const int ly  = (tid >> 2) & 7;           // 0..7
    const int lz  = tid & 3;                  // 0..3 -> z and z+4

    const float b      = 1.5f * r;
    const float r15sq  = b * b;
    const float rr     = r * r;
    const float E2     = 7.3890562f;
    const float c2a    = 4.0f / (E2 * rr);
    const float c2b    = 12.0f / (E2 * r);
    const float c2c    = 9.0f / E2;
    const float n2orr  = -2.0f / rr;

    const float px0 = 0.5f * (float)(tx * 8 + lx);
    const float px1 = px0 + 2.0f;
    const float py  = 0.5f * (float)(ty * 8 + ly);
    const float pz0 = 0.5f * (float)(tz * 8 + lz);
    const float pz1 = pz0 + 2.0f;

    __shared__ float4 sa[128];
    const unsigned short* __restrict__ lst = lists + (size_t)lt * CAP;

    float acc00 = 0.0f, acc01 = 0.0f, acc10 = 0.0f, acc11 = 0.0f;

    for (int base = start; base < end; base += 128) {
        const int m = min(128, end - base);
        if (tid < m) {
            const int idx = (int)lst[base + tid];
            sa[tid] = make_float4(vecs[3 * idx + 0] + 23.5f,
                                  vecs[3 * idx + 1] + 23.5f,
                                  vecs[3 * idx + 2] + 23.5f, 0.0f);
        }
        __syncthreads();

        int j = 0;
        for (; j + 1 < m; j += 2) {
            const float4 a0 = sa[j];
            const float4 a1 = sa[j + 1];
            EVAL_ATOM(a0);
            EVAL_ATOM(a1);
        }
        if (j < m) {
            const float4 a0 = sa[j];
            EVAL_ATOM(a0);
        }
        __syncthreads();
    }

    // store 512 partials: layout [cell 0..511] with cell = ((X*8)+Y)*8+Z local
    // local cell index: x=lx(+4), y=ly, z=lz(+4)
    float* __restrict__ cp = copies + ((size_t)lt * MAXSEG + s) * 512;
    const int c00 = ((lx      * 8) + ly) * 8 + lz;
    const int c01 = ((lx      * 8) + ly) * 8 + lz + 4;
    const int c10 = (((lx + 4) * 8) + ly) * 8 + lz;
    const int c11 = (((lx + 4) * 8) + ly) * 8 + lz + 4;
    cp[c00] = acc00;
    cp[c01] = acc01;
    cp[c10] = acc10;
    cp[c11] = acc11;
}

// Phase 3: one block per (tile,type). Sums only the segments that stored
// (ss*len < n — exactly gather's store condition), fixed order, writes the
// tile's 512 output cells once (zeros for inactive tiles).
__global__ __launch_bounds__(256) void reduce_kernel(
    const int* __restrict__ cnt, const float* __restrict__ copies,
    float* __restrict__ out, int nseg)
{
    const int type = blockIdx.y;
    const int t = blockIdx.x;
    const int tx = t / (NT * NT);
    const int ty = (t / NT) % NT;
    const int tz = t % NT;
    const int tid = threadIdx.x;
    // cell index pair: local cells tid and tid+256 in [((X*8)+Y)*8+Z] layout
    const int lx0 = tid >> 6;              // 0..3
    const int ly  = (tid >> 3) & 7;
    const int lz  = tid & 7;

    const int lt  = type * NTILES + t;
    const int n   = min(cnt[lt], CAP);
    const int len = (n + nseg - 1) / nseg;
    const float* __restrict__ cp = copies + ((size_t)lt * MAXSEG) * 512;

    const int c0 = ((lx0      * 8) + ly) * 8 + lz;   // = tid
    const int c1 = (((lx0 + 4) * 8) + ly) * 8 + lz;  // = tid + 256

    float o0 = 0.0f, o1 = 0.0f;
    for (int ss = 0; ss < nseg; ++ss) {
        if (ss * len >= n) break;            // segment never stored
        o0 += cp[(size_t)ss * 512 + c0];
        o1 += cp[(size_t)ss * 512 + c1];
    }

    const int X0 = tx * 8 + lx0;
    const int Y  = ty * 8 + ly;
    const int Z  = tz * 8 + lz;
    float* __restrict__ o = out + (size_t)type * NG * NG * NG;
    o[((X0      * NG) + Y) * NG + Z] = o0;
    o[(((X0 + 4) * NG) + Y) * NG + Z] = o1;
}

extern "C" void kernel_launch(void* const* d_in, const int* in_sizes, int n_in,
                              void* d_out, int out_size, void* d_ws, size_t ws_size,
                              hipStream_t stream) {
    const float* vC = (const float*)d_in[0];
    const float* vN = (const float*)d_in[1];
    const float* vO = (const float*)d_in[2];
    float* out = (float*)d_out;

    int* cnt = (int*)d_ws;
    unsigned short* lists = (unsigned short*)((char*)d_ws + LISTS_OFF);
    float* copies = (float*)((char*)d_ws + COPIES_OFF);

    const size_t copy_bytes = (size_t)3 * NTILES * MAXSEG * 512 * sizeof(float);
    int nseg = (ws_size >= COPIES_OFF + copy_bytes) ? MAXSEG : 4;

    const int natoms = in_sizes[0] / 3;   // 16384

    hipMemsetAsync(cnt, 0, 3 * NTILES * sizeof(int), stream);

    dim3 bgrid((natoms + 511) / 512, 3, 1);
    bin_kernel<<<bgrid, 512, 0, stream>>>(vC, vN, vO, cnt, lists, natoms);

    dim3 ggrid(NTILES * nseg, 3, 1);
    gather_seg<<<ggrid, 128, 0, stream>>>(vC, vN, vO, cnt, lists, copies, nseg);

    dim3 rgrid(NTILES, 3, 1);
    reduce_kernel<<<rgrid, 256, 0, stream>>>(cnt, copies, out, nseg);
}